// Round 6
// baseline (454.252 us; speedup 1.0000x reference)
//
#include <hip/hip_runtime.h>
#include <hip/hip_bf16.h>
#include <math.h>

// StyleGAN3 SynthesisLayer forward, MI355X.
// B=16, CIN=COUT=256, H=W=64, K=3, up=2 down=2 taps=12, conv out 66x66,
// up-FIR out 138x138, final out 64x64.

typedef __attribute__((ext_vector_type(8))) short bf16x8;
typedef __attribute__((ext_vector_type(4))) float f32x4;

#define NM 69696         // 16*66*66 flattened conv-output positions
#define SPI 4356         // 66*66 spatial per image

__device__ inline void gload16(const void* g, void* l) {
  __builtin_amdgcn_global_load_lds((const __attribute__((address_space(1))) void*)g,
                                   (__attribute__((address_space(3))) void*)l, 16, 0, 0);
}

// ---------- styles = w @ aw^T / sqrt(512) + ab ----------
__global__ __launch_bounds__(256) void k_styles(
    const float* __restrict__ w, const float* __restrict__ aw,
    const float* __restrict__ ab, float* __restrict__ styles) {
  __shared__ float lw[512];
  int b = blockIdx.x, t = threadIdx.x;
  lw[t] = w[b * 512 + t];
  lw[t + 256] = w[b * 512 + t + 256];
  __syncthreads();
  const float* row = aw + (long)t * 512;
  float acc = 0.f;
  #pragma unroll 4
  for (int d = 0; d < 512; ++d) acc += row[d] * lw[d];
  styles[b * 256 + t] = acc * 0.04419417382415922f + ab[t];
}

// ---------- scal[0] = 1/mean(styles^2), scal[1] = rsqrt(ema) ----------
__global__ __launch_bounds__(256) void k_scalars(
    const float* __restrict__ styles, const float* __restrict__ ema,
    float* __restrict__ scal) {
  __shared__ float red[256];
  int t = threadIdx.x;
  float s = 0.f;
  #pragma unroll
  for (int k = 0; k < 16; ++k) { float v = styles[t + k * 256]; s += v * v; }
  red[t] = s; __syncthreads();
  for (int off = 128; off > 0; off >>= 1) {
    if (t < off) red[t] += red[t + off];
    __syncthreads();
  }
  if (t == 0) { scal[0] = 4096.0f / red[0]; scal[1] = 1.0f / sqrtf(ema[0]); }
}

// ---------- per-o weight norm; wsq[o][i]; wbt[tap][o][i] bf16 ----------
__global__ __launch_bounds__(256) void k_wnorm(
    const float* __restrict__ cw, float* __restrict__ wsq,
    __hip_bfloat16* __restrict__ wbt) {
  __shared__ float red[256];
  __shared__ float lws, lws2;
  int o = blockIdx.x, t = threadIdx.x;
  const float* base = cw + o * 2304;
  float s = 0.f;
  #pragma unroll
  for (int k = 0; k < 9; ++k) { float v = base[t + k * 256]; s += v * v; }
  red[t] = s; __syncthreads();
  for (int off = 128; off > 0; off >>= 1) {
    if (t < off) red[t] += red[t + off];
    __syncthreads();
  }
  if (t == 0) { lws2 = 2304.0f / red[0]; lws = sqrtf(lws2); }
  __syncthreads();
  const float* r9 = base + t * 9;
  float s9 = 0.f;
  #pragma unroll
  for (int k = 0; k < 9; ++k) s9 += r9[k] * r9[k];
  wsq[o * 256 + t] = lws2 * s9;
  #pragma unroll
  for (int tap = 0; tap < 9; ++tap)
    wbt[(tap * 256 + o) * 256 + t] = __float2bfloat16(r9[tap] * lws);
}

// ---------- dcoefs[b][o] = rsqrt(sum_i s^2 * wsq + 1e-8) * input_gain ----------
__global__ __launch_bounds__(256) void k_dcoefs(
    const float* __restrict__ styles, const float* __restrict__ wsq,
    const float* __restrict__ scal, float* __restrict__ dco) {
  __shared__ float sn2[256];
  int b = blockIdx.x, t = threadIdx.x;
  float v = styles[b * 256 + t];
  sn2[t] = v * v * scal[0];
  __syncthreads();
  const float* wr = wsq + t * 256;
  float acc = 0.f;
  #pragma unroll 4
  for (int i = 0; i < 256; ++i) acc += sn2[i] * wr[i];
  dco[b * 256 + t] = (1.0f / sqrtf(acc + 1e-8f)) * scal[1];
}

// ---------- xs_pad[b][68][68][256] bf16, NHWC, style-scaled, 2px zero border ----------
__global__ __launch_bounds__(256) void k_xpad(
    const float* __restrict__ x, const float* __restrict__ styles,
    const float* __restrict__ scal, unsigned short* __restrict__ xp) {
  __shared__ float lx[64 * 65];
  __shared__ float sc[64];
  int ig = blockIdx.x, hp = blockIdx.y, b = blockIdx.z, t = threadIdx.x;
  int i0 = ig * 64;
  float ss = sqrtf(scal[0]);
  if (t < 64) sc[t] = styles[b * 256 + i0 + t] * ss;
  int h = hp - 2;
  bool inh = (hp >= 2) && (hp < 66);
  if (inh) {
    #pragma unroll
    for (int p = 0; p < 16; ++p) {
      int idx = p * 256 + t; int i = idx >> 6, w = idx & 63;
      lx[i * 65 + w] = x[((b * 256 + i0 + i) * 64 + h) * 64 + w];
    }
  }
  __syncthreads();
  unsigned short* dst = xp + ((long)(b * 68 + hp) * 68) * 256 + i0;
  #pragma unroll
  for (int p = 0; p < 17; ++p) {
    int idx = p * 256 + t; int wp = idx >> 6, i = idx & 63;
    float v = 0.f;
    if (inh && wp >= 2 && wp < 66) v = lx[i * 65 + (wp - 2)] * sc[i];
    __hip_bfloat16 bv = __float2bfloat16(v);
    dst[wp * 256 + i] = *(unsigned short*)&bv;
  }
}

// ---------- conv v5: slab-reuse implicit GEMM ----------
// One block = 256 consecutive m of ONE image (tiles snapped to image bounds;
// 18 tiles/image, last padded/masked) x 128 o-half. 512 threads = 8 waves
// (4m x 2n), per-wave 64m x 64o, acc 4x4 (proven R1 geometry).
// Per ch-chunk (32 ch): stage a 7-row x 68-px x 64B input slab ONCE
// (contiguous 1KB/wave-instr), reuse across all 9 taps via LDS offsets
// (tap shift = ky*68+kx pixels, NHWC => 16B aligned). Cuts gload_lds count
// 288 -> ~105/thread and makes A-staging coalesced (R4 diagnosis: ~107cyc
// service per scattered gload instr dominated the kernel).
// A-slab swizzle: slot = 4*px + (g ^ ((px>>1)&3)) -> 8 distinct bank-quads
// per 16 consecutive px (2-way, free); staging source carries the inverse.
// B keeps R3's paired-row layout. Counted vmcnt (never 0 in loop), A/B dbuf:
// LDS = 2x32KB + 2x8KB = 80KB -> 2 blocks/CU.
__global__ __launch_bounds__(512, 4) void k_conv(
    const unsigned short* __restrict__ xp, const unsigned short* __restrict__ wbt,
    const float* __restrict__ dco, const float* __restrict__ bias,
    float* __restrict__ y) {
  __shared__ __align__(16) unsigned short As[2][16384];  // 2 x 32KB (2048 slots)
  __shared__ __align__(16) unsigned short Bs[2][4096];   // 2 x 8KB
  const int t = threadIdx.x;
  const int lane = t & 63;
  const int wave = t >> 6;
  const int wm = wave >> 1, wn = wave & 1;
  const int g = lane >> 4;                 // k 16B-chunk 0..3

  // XCD swizzle: 576 = 8*72 (divisible -> simple bijection)
  const int f = blockIdx.x;
  const int wgid = (f & 7) * 72 + (f >> 3);
  const int oh = wgid & 1;                 // o half (0/1)
  const int mt = wgid >> 1;                // 0..287
  const int b  = mt / 18;
  const int kt = mt - b * 18;
  const int mstart = kt * 256;             // local m start within image
  const int r0 = mstart / 66;              // first output row of tile

  // per-thread A-fragment pixel bases (slab-relative), 4 fm
  int pxbase[4];
  #pragma unroll
  for (int fm = 0; fm < 4; ++fm) {
    int m = mstart + wm * 64 + fm * 16 + (lane & 15);
    int rr = m / 66; int cc = m - rr * 66;
    pxbase[fm] = (rr - r0) * 68 + cc;      // <= 4*68+65; +tap <= 475 < 476
  }
  // B staging statics (paired-row layout, 512 tasks cover 8KB)
  int bstat;
  {
    int L = t >> 3, phys = t & 7;
    int raw = phys ^ (L & 7);
    int orow = 2 * L + (raw >> 2);
    int bkc = raw & 3;
    bstat = orow * 512 + bkc * 16;         // byte offset within (tap,ch) panel
  }
  f32x4 acc[4][4] = {};
  const char* xb = (const char*)xp;
  const char* wb2 = (const char*)wbt + oh * 65536;   // fold o-half into base
  char* asb = (char*)As;
  char* bsb = (char*)Bs;

  // A-slab stage: round r (0..3) of channel-chunk ch1 into As[ch1&1]
  auto stageA = [&](int ch1, int r) {
    int task = r * 512 + t; if (task > 1903) task = 1903;  // clamp (dup, unread)
    int px = task >> 2, cph = task & 3;
    int srow = px / 68; int scol = px - srow * 68;
    int row = r0 + srow; if (row > 67) row = 67;
    int csrc = cph ^ ((px >> 1) & 3);
    const char* src = xb + (((b * 68 + row) * 68 + scol) << 9) + (ch1 << 6) + (csrc << 4);
    gload16(src, asb + ((ch1 & 1) << 15) + ((r * 512 + t) << 4));
  };
  // B stage: (tap,ch) panel into Bs[buf]
  auto stageB = [&](int tap, int ch, int buf) {
    const char* src = wb2 + tap * 131072 + ch * 64 + bstat;
    gload16(src, bsb + (buf << 13) + (t << 4));
  };

  // prologue: A[0] (4 rounds) + B(0,0) -> drain, barrier
  stageA(0, 0); stageA(0, 1); stageA(0, 2); stageA(0, 3);
  stageB(0, 0, 0);
  asm volatile("s_waitcnt vmcnt(0)" ::: "memory");
  __builtin_amdgcn_s_barrier();
  __builtin_amdgcn_sched_barrier(0);

  int pb = 0;                              // B read-buffer parity
  for (int ch = 0; ch < 8; ++ch) {
    const char* abuf = asb + ((ch & 1) << 15);
    const int ch1 = (ch == 7) ? 0 : ch + 1;
    #pragma unroll
    for (int tap = 0; tap < 9; ++tap) {
      // issue next stages (A: rounds on taps 0..3; B: next step's panel)
      if (tap < 4) stageA(ch1, tap);
      {
        int tapn = (tap == 8) ? 0 : tap + 1;
        int chn = (tap == 8) ? ch1 : ch;   // (7,8) -> dummy (0,0), harmless
        stageB(tapn, chn, pb ^ 1);
      }
      // counted wait: drain through last step's B (leaves this step's issues)
      if (tap < 4) asm volatile("s_waitcnt vmcnt(2)" ::: "memory");
      else         asm volatile("s_waitcnt vmcnt(1)" ::: "memory");
      __builtin_amdgcn_s_barrier();
      // compute
      const int koff = (tap / 3) * 68 + (tap % 3);    // compile-time
      bf16x8 av[4], bv[4];
      #pragma unroll
      for (int fm = 0; fm < 4; ++fm) {
        int px = pxbase[fm] + koff;
        int slot = (px << 2) + (g ^ ((px >> 1) & 3));
        av[fm] = *(const bf16x8*)(abuf + (slot << 4));
      }
      #pragma unroll
      for (int fn = 0; fn < 4; ++fn) {
        int brow = wn * 64 + fn * 16 + (lane & 15);
        int L = brow >> 1;
        int phys = (((brow & 1) << 2) | g) ^ (L & 7);
        bv[fn] = *(const bf16x8*)(bsb + (pb << 13) + L * 128 + phys * 16);
      }
      __builtin_amdgcn_s_setprio(1);
      #pragma unroll
      for (int fm = 0; fm < 4; ++fm)
        #pragma unroll
        for (int fn = 0; fn < 4; ++fn)
          acc[fm][fn] = __builtin_amdgcn_mfma_f32_16x16x32_bf16(
              av[fm], bv[fn], acc[fm][fn], 0, 0, 0);
      __builtin_amdgcn_s_setprio(0);
      __builtin_amdgcn_sched_barrier(0);
      __builtin_amdgcn_s_barrier();
      pb ^= 1;
    }
  }
  asm volatile("s_waitcnt vmcnt(0)" ::: "memory");
  __builtin_amdgcn_s_barrier();

  // Epilogue: scale + bias, transpose via LDS slab [256m][17], write NCHW.
  float* slab = (float*)As;
  const float* dcrow = dco + b * 256 + oh * 128;
  #pragma unroll
  for (int s = 0; s < 8; ++s) {
    if (wn == (s >> 2)) {
      const int sfn = s & 3;
      int ocol = lane & 15;
      float bo = bias[oh * 128 + s * 16 + ocol];
      float dc = dcrow[s * 16 + ocol];
      #pragma unroll
      for (int fm = 0; fm < 4; ++fm) {
        #pragma unroll
        for (int j = 0; j < 4; ++j) {
          int lm = wm * 64 + fm * 16 + ((lane >> 4) << 2) + j;
          slab[lm * 17 + ocol] = acc[fm][sfn][j] * dc + bo;
        }
      }
    }
    __syncthreads();
    int oc2 = t >> 5;                       // 0..15
    int og2 = oh * 128 + s * 16 + oc2;
    #pragma unroll
    for (int p = 0; p < 8; ++p) {
      int lm = (t & 31) + p * 32;
      int sp = mstart + lm;
      if (sp < SPI)
        y[(long)(b * 256 + og2) * SPI + sp] = slab[lm * 17 + oc2];
    }
    __syncthreads();
  }
}

// ---------- filtered_lrelu: column-strip, vectorized LDS ----------
struct Filt { float f[12]; };

__global__ __launch_bounds__(256) void k_lrelu(
    const float* __restrict__ y, float* __restrict__ out, Filt ft) {
  __shared__ __align__(16) float t1[3864];    // [138][28]
  __shared__ __align__(16) float t2[6072];    // [138][44]
  float* bufY = t2;                           // [66][28] overlays t2
  float* t3 = t1;                             // [64][44] overlays t1
  const int t = threadIdx.x;
  const int strip = blockIdx.x & 3;
  const long img = blockIdx.x >> 2;
  const int c0 = strip * 16;
  const float* ysrc = y + img * SPI;

  // phase 1: bufY[66][28], cols c0-4..c0+21 in slots 0..25, rest 0
  #pragma unroll
  for (int p = 0; p < 8; ++p) {
    int e = p * 256 + t;
    if (e < 1848) {
      int r = e / 28, lc = e - r * 28;
      int c = c0 - 4 + lc;
      bufY[e] = (lc < 26 && c >= 0 && c < 66) ? ysrc[r * 66 + c] : 0.f;
    }
  }
  __syncthreads();

  // phase 2: vertical up-FIR -> t1 [138][28], float4 col-quads
  #pragma unroll
  for (int p = 0; p < 4; ++p) {
    int e = p * 256 + t;
    if (e < 966) {                        // 138 rows x 7 quads
      int rr = e / 7, q = e - rr * 7;
      int p0 = (rr + 1) & 1;
      int yr0 = (rr + p0 - 9) >> 1;
      float4 a = make_float4(0.f, 0.f, 0.f, 0.f);
      #pragma unroll
      for (int j = 0; j < 6; ++j) {
        int yr = yr0 + j;
        if (yr >= 0 && yr < 66) {
          float cf = ft.f[2 * j + p0];
          float4 v = *(const float4*)&bufY[yr * 28 + 4 * q];
          a.x += cf * v.x; a.y += cf * v.y; a.z += cf * v.z; a.w += cf * v.w;
        }
      }
      *(float4*)&t1[rr * 28 + 4 * q] =
          make_float4(2.f * a.x, 2.f * a.y, 2.f * a.z, 2.f * a.w);
    }
  }
  __syncthreads();

  // phase 3: horizontal up-FIR + lrelu*sqrt2 + clamp -> t2 [138][44]
  #pragma unroll
  for (int p = 0; p < 6; ++p) {
    int e = p * 256 + t;
    if (e < 1518) {                       // 138 rows x 11 quads
      int rr = e / 11, v = e - rr * 11;
      const float* tr = t1 + rr * 28 + 2 * v;
      float2 w0 = *(const float2*)(tr + 0);
      float2 w1 = *(const float2*)(tr + 2);
      float2 w2 = *(const float2*)(tr + 4);
      float2 w3 = *(const float2*)(tr + 6);
      float w[8] = {w0.x, w0.y, w1.x, w1.y, w2.x, w2.y, w3.x, w3.y};
      float a0 = 0.f, a1 = 0.f, a2 = 0.f, a3 = 0.f;
      #pragma unroll
      for (int j = 0; j < 6; ++j) {
        float fe = ft.f[2 * j], fo = ft.f[2 * j + 1];
        a0 += fo * w[j];
        a1 += fe * w[j];
        a2 += fo * w[j + 1];
        a3 += fe * w[j + 1];
      }
      float4 r;
      r.x = a0 * 2.f; r.y = a1 * 2.f; r.z = a2 * 2.f; r.w = a3 * 2.f;
      r.x = (r.x < 0.f ? 0.2f * r.x : r.x) * 1.41421356237f;
      r.y = (r.y < 0.f ? 0.2f * r.y : r.y) * 1.41421356237f;
      r.z = (r.z < 0.f ? 0.2f * r.z : r.z) * 1.41421356237f;
      r.w = (r.w < 0.f ? 0.2f * r.w : r.w) * 1.41421356237f;
      r.x = fminf(fmaxf(r.x, -256.f), 256.f);
      r.y = fminf(fmaxf(r.y, -256.f), 256.f);
      r.z = fminf(fmaxf(r.z, -256.f), 256.f);
      r.w = fminf(fmaxf(r.w, -256.f), 256.f);
      *(float4*)&t2[rr * 44 + 4 * v] = r;
    }
  }
  __syncthreads();

  // phase 4: vertical down-FIR (stride 2) -> t3 [64][44], float4 quads
  #pragma unroll
  for (int p = 0; p < 3; ++p) {
    int e = p * 256 + t;
    if (e < 704) {                        // 64 rows x 11 quads
      int pp = e / 11, v = e - pp * 11;
      const float* col = t2 + (2 * pp) * 44 + 4 * v;
      float4 a = make_float4(0.f, 0.f, 0.f, 0.f);
      #pragma unroll
      for (int j = 0; j < 12; ++j) {
        float cf = ft.f[j];
        float4 x4 = *(const float4*)&col[j * 44];
        a.x += cf * x4.x; a.y += cf * x4.y; a.z += cf * x4.z; a.w += cf * x4.w;
      }
      *(float4*)&t3[pp * 44 + 4 * v] = a;
    }
  }
  __syncthreads();

  // phase 5: horizontal down-FIR (stride 2) + store, 4 outs/thread
  {
    int pp = t >> 2, v = t & 3;           // 64 rows x 4 quads = 256 tasks
    const float* row = t3 + pp * 44 + 8 * v;
    float w[20];
    #pragma unroll
    for (int k = 0; k < 5; ++k) {
      float4 x4 = *(const float4*)&row[4 * k];
      w[4 * k] = x4.x; w[4 * k + 1] = x4.y; w[4 * k + 2] = x4.z; w[4 * k + 3] = x4.w;
    }
    float a0 = 0.f, a1 = 0.f, a2 = 0.f, a3 = 0.f;
    #pragma unroll
    for (int j = 0; j < 12; ++j) {
      float cf = ft.f[j];
      a0 += cf * w[j]; a1 += cf * w[j + 2]; a2 += cf * w[j + 4]; a3 += cf * w[j + 6];
    }
    *(float4*)&out[img * 4096 + pp * 64 + c0 + 4 * v] = make_float4(a0, a1, a2, a3);
  }
}

// ---------- host ----------
static double bessel_i0(double x) {
  double q = x * x * 0.25, term = 1.0, sum = 1.0;
  for (int k = 1; k < 64; ++k) {
    term *= q / ((double)k * (double)k);
    sum += term;
    if (term < sum * 1e-18) break;
  }
  return sum;
}

extern "C" void kernel_launch(void* const* d_in, const int* in_sizes, int n_in,
                              void* d_out, int out_size, void* d_ws, size_t ws_size,
                              hipStream_t stream) {
  const float* x   = (const float*)d_in[0];
  const float* w   = (const float*)d_in[1];
  const float* aw  = (const float*)d_in[2];
  const float* ab  = (const float*)d_in[3];
  const float* cw  = (const float*)d_in[4];
  const float* cb  = (const float*)d_in[5];
  const float* ema = (const float*)d_in[6];
  float* out = (float*)d_out;
  char* ws = (char*)d_ws;

  float* styles        = (float*)(ws + 0);          // 16 KB
  float* scal          = (float*)(ws + 16384);      // 16 B
  float* wsq           = (float*)(ws + 16640);      // 256 KB
  float* dco           = (float*)(ws + 278784);     // 16 KB
  __hip_bfloat16* wbt  = (__hip_bfloat16*)(ws + 295168);   // 1.18 MB  [9][256][256]
  unsigned short* xp   = (unsigned short*)(ws + 1474816);  // 37.9 MB  [16][68][68][256]
  float* y             = (float*)(ws + 39354624);   // 71.4 MB  [16][256][66][66]

  // firwin(12, 16, width=32, fs=128) with Kaiser window (double precision)
  Filt ft;
  {
    double atten = 2.285 * 11.0 * M_PI * 0.5 + 7.95;
    double beta;
    if (atten > 50.0) beta = 0.1102 * (atten - 8.7);
    else if (atten > 21.0) beta = 0.5842 * pow(atten - 21.0, 0.4) + 0.07886 * (atten - 21.0);
    else beta = 0.0;
    double i0b = bessel_i0(beta);
    double h[12], ssum = 0.0;
    for (int n = 0; n < 12; ++n) {
      double xx = ((double)n - 5.5) / 5.5;
      double win = bessel_i0(beta * sqrt(1.0 - xx * xx)) / i0b;
      double mm = ((double)n - 5.5) * 0.25;
      double snc = sin(M_PI * mm) / (M_PI * mm);
      h[n] = 0.25 * snc * win;
      ssum += h[n];
    }
    for (int n = 0; n < 12; ++n) ft.f[n] = (float)(h[n] / ssum);
  }

  k_styles <<<16, 256, 0, stream>>>(w, aw, ab, styles);
  k_scalars<<<1, 256, 0, stream>>>(styles, ema, scal);
  k_wnorm  <<<256, 256, 0, stream>>>(cw, wsq, wbt);
  k_dcoefs <<<16, 256, 0, stream>>>(styles, wsq, scal, dco);
  k_xpad   <<<dim3(4, 68, 16), 256, 0, stream>>>(x, styles, scal, xp);
  k_conv   <<<576, 512, 0, stream>>>(xp, (const unsigned short*)wbt, dco, cb, y);
  k_lrelu  <<<16384, 256, 0, stream>>>(y, out, ft);
}

// Round 8
// 438.184 us; speedup vs baseline: 1.0367x; 1.0367x over previous
//
#include <hip/hip_runtime.h>
#include <hip/hip_bf16.h>
#include <math.h>

// StyleGAN3 SynthesisLayer forward, MI355X.
// B=16, CIN=COUT=256, H=W=64, K=3, up=2 down=2 taps=12, conv out 66x66,
// up-FIR out 138x138, final out 64x64.

typedef __attribute__((ext_vector_type(8))) short bf16x8;
typedef __attribute__((ext_vector_type(4))) float f32x4;

#define NM 69696         // 16*66*66 flattened conv-output positions
#define SPI 4356         // 66*66 spatial per image

__device__ inline void gload16(const void* g, void* l) {
  __builtin_amdgcn_global_load_lds((const __attribute__((address_space(1))) void*)g,
                                   (__attribute__((address_space(3))) void*)l, 16, 0, 0);
}

// ---------- styles = w @ aw^T / sqrt(512) + ab ----------
__global__ __launch_bounds__(256) void k_styles(
    const float* __restrict__ w, const float* __restrict__ aw,
    const float* __restrict__ ab, float* __restrict__ styles) {
  __shared__ float lw[512];
  int b = blockIdx.x, t = threadIdx.x;
  lw[t] = w[b * 512 + t];
  lw[t + 256] = w[b * 512 + t + 256];
  __syncthreads();
  const float* row = aw + (long)t * 512;
  float acc = 0.f;
  #pragma unroll 4
  for (int d = 0; d < 512; ++d) acc += row[d] * lw[d];
  styles[b * 256 + t] = acc * 0.04419417382415922f + ab[t];
}

// ---------- scal[0] = 1/mean(styles^2), scal[1] = rsqrt(ema) ----------
__global__ __launch_bounds__(256) void k_scalars(
    const float* __restrict__ styles, const float* __restrict__ ema,
    float* __restrict__ scal) {
  __shared__ float red[256];
  int t = threadIdx.x;
  float s = 0.f;
  #pragma unroll
  for (int k = 0; k < 16; ++k) { float v = styles[t + k * 256]; s += v * v; }
  red[t] = s; __syncthreads();
  for (int off = 128; off > 0; off >>= 1) {
    if (t < off) red[t] += red[t + off];
    __syncthreads();
  }
  if (t == 0) { scal[0] = 4096.0f / red[0]; scal[1] = 1.0f / sqrtf(ema[0]); }
}

// ---------- per-o weight norm; wsq[o][i]; wbt[tap][cc][o][32ci] bf16 ----------
__global__ __launch_bounds__(256) void k_wnorm(
    const float* __restrict__ cw, float* __restrict__ wsq,
    __hip_bfloat16* __restrict__ wbt) {
  __shared__ float red[256];
  __shared__ float lws, lws2;
  int o = blockIdx.x, t = threadIdx.x;
  const float* base = cw + o * 2304;
  float s = 0.f;
  #pragma unroll
  for (int k = 0; k < 9; ++k) { float v = base[t + k * 256]; s += v * v; }
  red[t] = s; __syncthreads();
  for (int off = 128; off > 0; off >>= 1) {
    if (t < off) red[t] += red[t + off];
    __syncthreads();
  }
  if (t == 0) { lws2 = 2304.0f / red[0]; lws = sqrtf(lws2); }
  __syncthreads();
  const float* r9 = base + t * 9;
  float s9 = 0.f;
  #pragma unroll
  for (int k = 0; k < 9; ++k) s9 += r9[k] * r9[k];
  wsq[o * 256 + t] = lws2 * s9;
  int cc = t >> 5, ci = t & 31;
  #pragma unroll
  for (int tap = 0; tap < 9; ++tap)
    wbt[(((tap * 8 + cc) * 256 + o) << 5) + ci] = __float2bfloat16(r9[tap] * lws);
}

// ---------- dcoefs[b][o] = rsqrt(sum_i s^2 * wsq + 1e-8) * input_gain ----------
__global__ __launch_bounds__(256) void k_dcoefs(
    const float* __restrict__ styles, const float* __restrict__ wsq,
    const float* __restrict__ scal, float* __restrict__ dco) {
  __shared__ float sn2[256];
  int b = blockIdx.x, t = threadIdx.x;
  float v = styles[b * 256 + t];
  sn2[t] = v * v * scal[0];
  __syncthreads();
  const float* wr = wsq + t * 256;
  float acc = 0.f;
  #pragma unroll 4
  for (int i = 0; i < 256; ++i) acc += sn2[i] * wr[i];
  dco[b * 256 + t] = (1.0f / sqrtf(acc + 1e-8f)) * scal[1];
}

// ---------- xs_pad chunked: xp[b][cc=8][68*68 px][32 ci] bf16, style-scaled ----------
__global__ __launch_bounds__(256) void k_xpad(
    const float* __restrict__ x, const float* __restrict__ styles,
    const float* __restrict__ scal, unsigned short* __restrict__ xp) {
  __shared__ float lx[64 * 65];
  __shared__ float sc[64];
  int ig = blockIdx.x, hp = blockIdx.y, b = blockIdx.z, t = threadIdx.x;
  int i0 = ig * 64;
  float ss = sqrtf(scal[0]);
  if (t < 64) sc[t] = styles[b * 256 + i0 + t] * ss;
  int h = hp - 2;
  bool inh = (hp >= 2) && (hp < 66);
  if (inh) {
    #pragma unroll
    for (int p = 0; p < 16; ++p) {
      int idx = p * 256 + t; int i = idx >> 6, w = idx & 63;
      lx[i * 65 + w] = x[((b * 256 + i0 + i) * 64 + h) * 64 + w];
    }
  }
  __syncthreads();
  // dst: [b][cc][px=hp*68+wp][ci]; this block covers cc = ig*2 + {0,1}
  unsigned short* dst = xp + (((long)(b * 8 + ig * 2) * 4624 + hp * 68) << 5);
  #pragma unroll
  for (int p = 0; p < 17; ++p) {
    int idx = p * 256 + t; int wp = idx >> 6, i = idx & 63;
    float v = 0.f;
    if (inh && wp >= 2 && wp < 66) v = lx[i * 65 + (wp - 2)] * sc[i];
    __hip_bfloat16 bv = __float2bfloat16(v);
    dst[(long)(i >> 5) * 147968 + wp * 32 + (i & 31)] = *(unsigned short*)&bv;
  }
}

// ---------- conv v6b: contiguous-slab implicit GEMM (v6 + 2 bugfixes) ----------
// Block = 256 m of ONE image x 128 o-half (576 blocks), 512 thr = 8 waves
// (4m x 2n), acc 4x4. Chunked xp layout -> per-cc A-slab is CONTIGUOUS and
// staged once per cc, reused by all 9 taps via LDS offsets. Chunked wbt ->
// each 8KB B-panel contiguous, L2-resident.
// FIX(R6): slab is 7 rows (5 output rows + ky<=2) = 476 px = 1904 tasks
//   (v6's 6-row slab dropped the bottom input row -> absmax 0.825).
// FIX(R6): vmcnt ladder restored to v5 invariant -- allow ONLY issues newer
//   than this step's reads: tap<4 -> vmcnt(2) (newest A-round + newest B),
//   tap>=4 -> vmcnt(1) (newest B). v6's 3/4/5 ladder let B(tap) float.
__global__ __launch_bounds__(512, 4) void k_conv(
    const unsigned short* __restrict__ xp, const unsigned short* __restrict__ wbt,
    const float* __restrict__ dco, const float* __restrict__ bias,
    float* __restrict__ y) {
  __shared__ __align__(16) unsigned short As[2][16384];  // 2 x 32KB
  __shared__ __align__(16) unsigned short Bs[2][4096];   // 2 x 8KB
  const int t = threadIdx.x;
  const int lane = t & 63;
  const int wave = t >> 6;
  const int wm = wave >> 1, wn = wave & 1;
  const int g = lane >> 4;                 // k 16B-chunk 0..3

  // XCD swizzle: 576 = 8*72
  const int f = blockIdx.x;
  const int wgid = (f & 7) * 72 + (f >> 3);
  const int oh = wgid & 1;                 // o half (0/1)
  const int mt = wgid >> 1;                // 0..287
  const int b  = mt / 18;
  const int kt = mt - b * 18;
  const int mstart = kt * 256;             // local m start within image
  const int r0 = mstart / 66;              // first output row of tile

  // per-thread A-fragment pixel bases (slab-relative; valid m: px+koff <= 475)
  int pxbase[4];
  #pragma unroll
  for (int fm = 0; fm < 4; ++fm) {
    int m = mstart + wm * 64 + fm * 16 + (lane & 15);
    int rr = m / 66; int cc_ = m - rr * 66;
    pxbase[fm] = (rr - r0) * 68 + cc_;
  }
  // B staging statics (paired-row layout; 512 tasks = 8KB half-panel)
  int bstat;
  {
    int L = t >> 3, phys = t & 7;
    int raw = phys ^ (L & 7);
    int orow = 2 * L + (raw >> 2);
    int bkc = raw & 3;
    bstat = orow * 64 + bkc * 16;          // bytes within contiguous panel
  }
  f32x4 acc[4][4] = {};
  const char* xb = (const char*)xp;
  const char* wb2 = (const char*)wbt + oh * 8192;  // o-half within panel
  char* asb = (char*)As;
  char* bsb = (char*)Bs;

  // A-slab stage: round r (0..3) of channel-chunk cc1 into As[cc1&1].
  // Slab = rows r0..r0+6 (7x68=476 px), tasks 0..1903; rounds pad to 2048
  // (dup src, lands in slots 1904+ which no valid fragment reads).
  auto stageA = [&](int cc1, int r) {
    int task = r * 512 + t;
    int ct = task > 1903 ? 1903 : task;
    int px = ct >> 2, cph = ct & 3;
    int srow = px / 68, scol = px - srow * 68;
    int row = r0 + srow; if (row > 67) row = 67;
    int csrc = cph ^ ((px >> 1) & 3);
    const char* src = xb + (((b * 8 + cc1) * 4624 + row * 68 + scol) << 6) + (csrc << 4);
    gload16(src, asb + ((cc1 & 1) << 15) + (task << 4));
  };
  // B stage: contiguous (tap,cc) panel into Bs[buf]
  auto stageB = [&](int tap, int cc, int buf) {
    const char* src = wb2 + (tap * 8 + cc) * 16384 + bstat;
    gload16(src, bsb + (buf << 13) + (t << 4));
  };

  // prologue: A slab(cc=0) rounds 0-3 + B(0,0) -> full drain once
  stageA(0, 0); stageA(0, 1); stageA(0, 2); stageA(0, 3);
  stageB(0, 0, 0);
  asm volatile("s_waitcnt vmcnt(0)" ::: "memory");
  __builtin_amdgcn_s_barrier();
  __builtin_amdgcn_sched_barrier(0);

  int pb = 0;                              // B read-buffer parity
  for (int ch = 0; ch < 8; ++ch) {
    const char* abuf = asb + ((ch & 1) << 15);
    const int ch1 = (ch + 1) & 7;
    #pragma unroll
    for (int tap = 0; tap < 9; ++tap) {
      // issue next stages: A-slab rounds on taps 0..3, next B panel always
      if (tap < 4) stageA(ch1, tap);
      {
        int tapn = (tap == 8) ? 0 : tap + 1;
        int chn = (tap == 8) ? ch1 : ch;
        stageB(tapn, chn, pb ^ 1);
      }
      // counted wait: retire everything except the issues newer than this
      // step's reads (newest A-round + newest B for tap<4, newest B after).
      if (tap < 4) asm volatile("s_waitcnt vmcnt(2)" ::: "memory");
      else         asm volatile("s_waitcnt vmcnt(1)" ::: "memory");
      __builtin_amdgcn_s_barrier();
      // compute
      const int koff = (tap / 3) * 68 + (tap % 3);    // compile-time
      bf16x8 av[4], bv[4];
      #pragma unroll
      for (int fm = 0; fm < 4; ++fm) {
        int px = pxbase[fm] + koff;
        int slot = (px << 2) + (g ^ ((px >> 1) & 3));
        av[fm] = *(const bf16x8*)(abuf + (slot << 4));
      }
      #pragma unroll
      for (int fn = 0; fn < 4; ++fn) {
        int brow = wn * 64 + fn * 16 + (lane & 15);
        int L = brow >> 1;
        int phys = (((brow & 1) << 2) | g) ^ (L & 7);
        bv[fn] = *(const bf16x8*)(bsb + (pb << 13) + L * 128 + phys * 16);
      }
      __builtin_amdgcn_s_setprio(1);
      #pragma unroll
      for (int fm = 0; fm < 4; ++fm)
        #pragma unroll
        for (int fn = 0; fn < 4; ++fn)
          acc[fm][fn] = __builtin_amdgcn_mfma_f32_16x16x32_bf16(
              av[fm], bv[fn], acc[fm][fn], 0, 0, 0);
      __builtin_amdgcn_s_setprio(0);
      __builtin_amdgcn_sched_barrier(0);
      __builtin_amdgcn_s_barrier();
      pb ^= 1;
    }
  }
  asm volatile("s_waitcnt vmcnt(0)" ::: "memory");
  __builtin_amdgcn_s_barrier();

  // Epilogue: scale + bias, transpose via LDS slab [256m][17], write NCHW.
  float* slab = (float*)As;
  const float* dcrow = dco + b * 256 + oh * 128;
  #pragma unroll
  for (int s = 0; s < 8; ++s) {
    if (wn == (s >> 2)) {
      const int sfn = s & 3;
      int ocol = lane & 15;
      float bo = bias[oh * 128 + s * 16 + ocol];
      float dc = dcrow[s * 16 + ocol];
      #pragma unroll
      for (int fm = 0; fm < 4; ++fm) {
        #pragma unroll
        for (int j = 0; j < 4; ++j) {
          int lm = wm * 64 + fm * 16 + ((lane >> 4) << 2) + j;
          slab[lm * 17 + ocol] = acc[fm][sfn][j] * dc + bo;
        }
      }
    }
    __syncthreads();
    int oc2 = t >> 5;                       // 0..15
    int og2 = oh * 128 + s * 16 + oc2;
    #pragma unroll
    for (int p = 0; p < 8; ++p) {
      int lm = (t & 31) + p * 32;
      int sp = mstart + lm;
      if (sp < SPI)
        y[(long)(b * 256 + og2) * SPI + sp] = slab[lm * 17 + oc2];
    }
    __syncthreads();
  }
}

// ---------- filtered_lrelu: column-strip, vectorized LDS ----------
struct Filt { float f[12]; };

__global__ __launch_bounds__(256) void k_lrelu(
    const float* __restrict__ y, float* __restrict__ out, Filt ft) {
  __shared__ __align__(16) float t1[3864];    // [138][28]
  __shared__ __align__(16) float t2[6072];    // [138][44]
  float* bufY = t2;                           // [66][28] overlays t2
  float* t3 = t1;                             // [64][44] overlays t1
  const int t = threadIdx.x;
  const int strip = blockIdx.x & 3;
  const long img = blockIdx.x >> 2;
  const int c0 = strip * 16;
  const float* ysrc = y + img * SPI;

  // phase 1: bufY[66][28], cols c0-4..c0+21 in slots 0..25, rest 0
  #pragma unroll
  for (int p = 0; p < 8; ++p) {
    int e = p * 256 + t;
    if (e < 1848) {
      int r = e / 28, lc = e - r * 28;
      int c = c0 - 4 + lc;
      bufY[e] = (lc < 26 && c >= 0 && c < 66) ? ysrc[r * 66 + c] : 0.f;
    }
  }
  __syncthreads();

  // phase 2: vertical up-FIR -> t1 [138][28], float4 col-quads
  #pragma unroll
  for (int p = 0; p < 4; ++p) {
    int e = p * 256 + t;
    if (e < 966) {                        // 138 rows x 7 quads
      int rr = e / 7, q = e - rr * 7;
      int p0 = (rr + 1) & 1;
      int yr0 = (rr + p0 - 9) >> 1;
      float4 a = make_float4(0.f, 0.f, 0.f, 0.f);
      #pragma unroll
      for (int j = 0; j < 6; ++j) {
        int yr = yr0 + j;
        if (yr >= 0 && yr < 66) {
          float cf = ft.f[2 * j + p0];
          float4 v = *(const float4*)&bufY[yr * 28 + 4 * q];
          a.x += cf * v.x; a.y += cf * v.y; a.z += cf * v.z; a.w += cf * v.w;
        }
      }
      *(float4*)&t1[rr * 28 + 4 * q] =
          make_float4(2.f * a.x, 2.f * a.y, 2.f * a.z, 2.f * a.w);
    }
  }
  __syncthreads();

  // phase 3: horizontal up-FIR + lrelu*sqrt2 + clamp -> t2 [138][44]
  #pragma unroll
  for (int p = 0; p < 6; ++p) {
    int e = p * 256 + t;
    if (e < 1518) {                       // 138 rows x 11 quads
      int rr = e / 11, v = e - rr * 11;
      const float* tr = t1 + rr * 28 + 2 * v;
      float2 w0 = *(const float2*)(tr + 0);
      float2 w1 = *(const float2*)(tr + 2);
      float2 w2 = *(const float2*)(tr + 4);
      float2 w3 = *(const float2*)(tr + 6);
      float w[8] = {w0.x, w0.y, w1.x, w1.y, w2.x, w2.y, w3.x, w3.y};
      float a0 = 0.f, a1 = 0.f, a2 = 0.f, a3 = 0.f;
      #pragma unroll
      for (int j = 0; j < 6; ++j) {
        float fe = ft.f[2 * j], fo = ft.f[2 * j + 1];
        a0 += fo * w[j];
        a1 += fe * w[j];
        a2 += fo * w[j + 1];
        a3 += fe * w[j + 1];
      }
      float4 r;
      r.x = a0 * 2.f; r.y = a1 * 2.f; r.z = a2 * 2.f; r.w = a3 * 2.f;
      r.x = (r.x < 0.f ? 0.2f * r.x : r.x) * 1.41421356237f;
      r.y = (r.y < 0.f ? 0.2f * r.y : r.y) * 1.41421356237f;
      r.z = (r.z < 0.f ? 0.2f * r.z : r.z) * 1.41421356237f;
      r.w = (r.w < 0.f ? 0.2f * r.w : r.w) * 1.41421356237f;
      r.x = fminf(fmaxf(r.x, -256.f), 256.f);
      r.y = fminf(fmaxf(r.y, -256.f), 256.f);
      r.z = fminf(fmaxf(r.z, -256.f), 256.f);
      r.w = fminf(fmaxf(r.w, -256.f), 256.f);
      *(float4*)&t2[rr * 44 + 4 * v] = r;
    }
  }
  __syncthreads();

  // phase 4: vertical down-FIR (stride 2) -> t3 [64][44], float4 quads
  #pragma unroll
  for (int p = 0; p < 3; ++p) {
    int e = p * 256 + t;
    if (e < 704) {                        // 64 rows x 11 quads
      int pp = e / 11, v = e - pp * 11;
      const float* col = t2 + (2 * pp) * 44 + 4 * v;
      float4 a = make_float4(0.f, 0.f, 0.f, 0.f);
      #pragma unroll
      for (int j = 0; j < 12; ++j) {
        float cf = ft.f[j];
        float4 x4 = *(const float4*)&col[j * 44];
        a.x += cf * x4.x; a.y += cf * x4.y; a.z += cf * x4.z; a.w += cf * x4.w;
      }
      *(float4*)&t3[pp * 44 + 4 * v] = a;
    }
  }
  __syncthreads();

  // phase 5: horizontal down-FIR (stride 2) + store, 4 outs/thread
  {
    int pp = t >> 2, v = t & 3;           // 64 rows x 4 quads = 256 tasks
    const float* row = t3 + pp * 44 + 8 * v;
    float w[20];
    #pragma unroll
    for (int k = 0; k < 5; ++k) {
      float4 x4 = *(const float4*)&row[4 * k];
      w[4 * k] = x4.x; w[4 * k + 1] = x4.y; w[4 * k + 2] = x4.z; w[4 * k + 3] = x4.w;
    }
    float a0 = 0.f, a1 = 0.f, a2 = 0.f, a3 = 0.f;
    #pragma unroll
    for (int j = 0; j < 12; ++j) {
      float cf = ft.f[j];
      a0 += cf * w[j]; a1 += cf * w[j + 2]; a2 += cf * w[j + 4]; a3 += cf * w[j + 6];
    }
    *(float4*)&out[img * 4096 + pp * 64 + c0 + 4 * v] = make_float4(a0, a1, a2, a3);
  }
}

// ---------- host ----------
static double bessel_i0(double x) {
  double q = x * x * 0.25, term = 1.0, sum = 1.0;
  for (int k = 1; k < 64; ++k) {
    term *= q / ((double)k * (double)k);
    sum += term;
    if (term < sum * 1e-18) break;
  }
  return sum;
}

extern "C" void kernel_launch(void* const* d_in, const int* in_sizes, int n_in,
                              void* d_out, int out_size, void* d_ws, size_t ws_size,
                              hipStream_t stream) {
  const float* x   = (const float*)d_in[0];
  const float* w   = (const float*)d_in[1];
  const float* aw  = (const float*)d_in[2];
  const float* ab  = (const float*)d_in[3];
  const float* cw  = (const float*)d_in[4];
  const float* cb  = (const float*)d_in[5];
  const float* ema = (const float*)d_in[6];
  float* out = (float*)d_out;
  char* ws = (char*)d_ws;

  float* styles        = (float*)(ws + 0);          // 16 KB
  float* scal          = (float*)(ws + 16384);      // 16 B
  float* wsq           = (float*)(ws + 16640);      // 256 KB
  float* dco           = (float*)(ws + 278784);     // 16 KB
  __hip_bfloat16* wbt  = (__hip_bfloat16*)(ws + 295168);   // 1.18 MB  [9][8cc][256o][32ci]
  unsigned short* xp   = (unsigned short*)(ws + 1474816);  // 37.9 MB  [16][8cc][68*68][32ci]
  float* y             = (float*)(ws + 39354624);   // 71.4 MB  [16][256][66][66]

  // firwin(12, 16, width=32, fs=128) with Kaiser window (double precision)
  Filt ft;
  {
    double atten = 2.285 * 11.0 * M_PI * 0.5 + 7.95;
    double beta;
    if (atten > 50.0) beta = 0.1102 * (atten - 8.7);
    else if (atten > 21.0) beta = 0.5842 * pow(atten - 21.0, 0.4) + 0.07886 * (atten - 21.0);
    else beta = 0.0;
    double i0b = bessel_i0(beta);
    double h[12], ssum = 0.0;
    for (int n = 0; n < 12; ++n) {
      double xx = ((double)n - 5.5) / 5.5;
      double win = bessel_i0(beta * sqrt(1.0 - xx * xx)) / i0b;
      double mm = ((double)n - 5.5) * 0.25;
      double snc = sin(M_PI * mm) / (M_PI * mm);
      h[n] = 0.25 * snc * win;
      ssum += h[n];
    }
    for (int n = 0; n < 12; ++n) ft.f[n] = (float)(h[n] / ssum);
  }

  k_styles <<<16, 256, 0, stream>>>(w, aw, ab, styles);
  k_scalars<<<1, 256, 0, stream>>>(styles, ema, scal);
  k_wnorm  <<<256, 256, 0, stream>>>(cw, wsq, wbt);
  k_dcoefs <<<16, 256, 0, stream>>>(styles, wsq, scal, dco);
  k_xpad   <<<dim3(4, 68, 16), 256, 0, stream>>>(x, styles, scal, xp);
  k_conv   <<<576, 512, 0, stream>>>(xp, (const unsigned short*)wbt, dco, cb, y);
  k_lrelu  <<<16384, 256, 0, stream>>>(y, out, ft);
}